// Round 11
// baseline (230.026 us; speedup 1.0000x reference)
//
#include <hip/hip_runtime.h>
#include <hip/hip_bf16.h>

// SPRGraphNet: embed -> 2x SAGEConv(mean) -> mean-pool per graph -> linear(64->10)
// Round 16: group-per-node gather. Round 17: LDS emb table for gather1.
// Round 18: code-only pass. Round 19: un-fused gather1 (gather needs occupancy).
// Round 20: MFMA layer kernels (wfrag pre-swizzled hi/lo bf16 weights).
// Round 21: 4-deep gather MLP (NULL -> gather is fabric-bound); convert folded.
// Round 22: lookback-scan REGRESSED (cross-XCD atomic handshake). Lesson.
// Round 23: scan reverted; pool at 1024 threads kept. 234.2us.
// Round 24: fused layer2+pool REGRESSED (hot-region global atomic bursts).
// Round 25: wfrag staged in LDS in layer_mfma (B-frags via ds_read_b128;
// VMEM loads 36->4/thread). 229.9us (best).
// Round 26: fold scanC into scatter1 -- stage bsum (<=1024 ints) in LDS,
// Hillis-Steele scan in-LDS, compute cur[bin] = tmp+prefix-H directly; block 0
// publishes bucketStart[512] for csr2 (B array + scanC launch eliminated;
// CSR bit-identical). 9 launches.
// Harness poison fills (~84us/iter at ~80% HBM peak) = floor.

typedef __attribute__((ext_vector_type(8))) short bf16x8;
typedef __attribute__((ext_vector_type(4))) float f32x4;

struct WParams {
    const void* p[10];
    int off[11];
};

__device__ __forceinline__ float b2f(unsigned short u) {
    return __uint_as_float(((unsigned)u) << 16);
}
__device__ __forceinline__ unsigned short f2b(float f) {
    unsigned x = __float_as_uint(f);
    return (unsigned short)((x + 0x7fff + ((x >> 16) & 1)) >> 16);   // RNE
}
__device__ __forceinline__ float blo(unsigned u) {   // low bf16 of a dword
    return __uint_as_float(u << 16);
}
__device__ __forceinline__ float bhi(unsigned u) {   // high bf16 of a dword
    return __uint_as_float(u & 0xffff0000u);
}

// Inline dtype detection: fp32 data read as bf16 shows |v|>100 / NaN.
template <int BS>
__device__ __forceinline__ int detect_f32(const void* probe, int n_bf16) {
    __shared__ int bad;
    if (threadIdx.x == 0) bad = 0;
    __syncthreads();
    const __hip_bfloat16* p = (const __hip_bfloat16*)probe;
    int lbad = 0;
    for (int i = threadIdx.x; i < n_bf16; i += BS) {
        float v = __bfloat162float(p[i]);
        if (!(fabsf(v) <= 100.0f)) lbad = 1;
    }
    if (lbad) atomicOr(&bad, 1);
    __syncthreads();
    return bad;
}

__device__ __forceinline__ float loadf(const void* p, int i, int f32) {
    return f32 ? ((const float*)p)[i]
               : __bfloat162float(((const __hip_bfloat16*)p)[i]);
}

// Blocks [0,NBE): LDS histogram of tgt&511 over a 4096-edge tile -> H[bin][blk].
// Blocks [NBE,NBE+CB): code[node] = x0*16+x1.
// Blocks [NBE+CB, +16): emb1024 bf16 table from RAW semb/cemb (detect inline).
// Blocks [NBE+CB+16, +8): wfrag (MFMA B-frag swizzled, hi/lo bf16) from RAW.
// Block  [NBE+CB+24]: pbuf fp32 params.
static __global__ __launch_bounds__(256) void hist1_code_kernel(
        const int* __restrict__ tgt, int* __restrict__ H, int NBE, int CB,
        const int* __restrict__ x, unsigned short* __restrict__ code,
        WParams wp,
        unsigned short* __restrict__ emb1024, unsigned short* __restrict__ wfrag,
        float* __restrict__ pbuf, int n_nodes, int n_edges) {
    int t = threadIdx.x;
    if (blockIdx.x < (unsigned)NBE) {
        __shared__ int lh[512];
        lh[t] = 0; lh[t + 256] = 0;
        __syncthreads();
        int base = blockIdx.x * 4096;              // multiple of 4
        const int4* tgt4 = (const int4*)tgt + (base >> 2);
#pragma unroll
        for (int r = 0; r < 4; ++r) {
            int i4 = t + 256 * r;
            int e = base + i4 * 4;
            if (e + 3 < n_edges) {
                int4 v = tgt4[i4];
                atomicAdd(&lh[v.x & 511], 1);
                atomicAdd(&lh[v.y & 511], 1);
                atomicAdd(&lh[v.z & 511], 1);
                atomicAdd(&lh[v.w & 511], 1);
            } else {
                for (int q = 0; q < 4; ++q) {
                    int ee = e + q;
                    if (ee < n_edges) atomicAdd(&lh[tgt[ee] & 511], 1);
                }
            }
        }
        __syncthreads();
        H[(size_t)t * NBE + blockIdx.x] = lh[t];
        H[(size_t)(t + 256) * NBE + blockIdx.x] = lh[t + 256];
    } else if (blockIdx.x < (unsigned)(NBE + CB)) {
        int node = (blockIdx.x - NBE) * 256 + t;
        if (node >= n_nodes) return;
        int2 xv = *(const int2*)&x[node * 2];
        code[node] = (unsigned short)(xv.x * 16 + xv.y);
    } else if (blockIdx.x < (unsigned)(NBE + CB + 16)) {
        int f32 = detect_f32<256>(wp.p[0], 1024);
        int bl = blockIdx.x - NBE - CB;
        for (int i = bl * 256 + t; i < 1024 * 64; i += 16 * 256) {
            int r = i >> 6, c = i & 63;
            float v = (c < 32) ? loadf(wp.p[0], (r >> 4) * 32 + c, f32)
                               : loadf(wp.p[1], (r & 15) * 32 + (c - 32), f32);
            emb1024[i] = f2b(v);
        }
    } else if (blockIdx.x < (unsigned)(NBE + CB + 24)) {
        int f32 = detect_f32<256>(wp.p[0], 1024);
        int bl = blockIdx.x - NBE - CB - 16;
        for (int i = bl * 256 + t; i < 32768; i += 8 * 256) {
            int j    = i & 7;
            int lane = (i >> 3) & 63;
            int nt   = (i >> 9) & 3;
            int ks   = (i >> 11) & 3;
            int part = (i >> 13) & 1;
            int L    = (i >> 14) & 1;
            int k = ks * 32 + (lane >> 4) * 8 + j;
            int c = nt * 16 + (lane & 15);
            const void* wl = L ? wp.p[5] : wp.p[2];
            const void* wr = L ? wp.p[6] : wp.p[3];
            float wv = (k < 64) ? loadf(wl, k * 64 + c, f32)
                                : loadf(wr, (k - 64) * 64 + c, f32);
            unsigned short hi = f2b(wv);
            wfrag[i] = (part == 0) ? hi : f2b(wv - b2f(hi));
        }
    } else {
        int f32 = detect_f32<256>(wp.p[0], 1024);
        for (int i = t; i < 778; i += 256) {
            float v;
            if (i < 64)       v = loadf(wp.p[4], i, f32);         // b1
            else if (i < 128) v = loadf(wp.p[7], i - 64, f32);    // b2
            else if (i < 768) v = loadf(wp.p[8], i - 128, f32);   // wc
            else              v = loadf(wp.p[9], i - 768, f32);   // bc
            pbuf[i] = v;
        }
    }
}

// scanA: 512 elements per block (2/thread), block-inclusive -> tmp, sums -> bsum.
static __global__ __launch_bounds__(256) void scanA_kernel(
        const int* __restrict__ in, int* __restrict__ tmp,
        int* __restrict__ bsum, int n) {
    __shared__ int s[256];
    int t = threadIdx.x;
    int i0 = blockIdx.x * 512 + 2 * t;
    int a0 = (i0 < n) ? in[i0] : 0;
    int a1 = (i0 + 1 < n) ? in[i0 + 1] : 0;
    s[t] = a0 + a1;
    __syncthreads();
#pragma unroll
    for (int d = 1; d < 256; d <<= 1) {
        int x = (t >= d) ? s[t - d] : 0;
        __syncthreads();
        s[t] += x;
        __syncthreads();
    }
    if (i0 < n) tmp[i0] = s[t] - a1;          // inclusive at i0
    if (i0 + 1 < n) tmp[i0 + 1] = s[t];       // inclusive at i0+1
    if (t == 255) bsum[blockIdx.x] = s[255];
}

// scatter1 (R26: scanC folded in). Stage bsum in LDS, scan it (Hillis-Steele,
// 1024-wide), cur[bin] = tmp[bin*NBE+blk] + prefix - H[bin*NBE+blk].
// Block 0 publishes bucketStart[512] (= cur before atomics) for csr2.
// Then re-read tile; LDS cursors give global slots; write packed records.
static __global__ __launch_bounds__(256) void scatter1_kernel(
        const int* __restrict__ src, const int* __restrict__ tgt,
        const int* __restrict__ tmp, const int* __restrict__ bsum,
        const int* __restrict__ H, int* __restrict__ bstart,
        unsigned* __restrict__ rec, int NBE, int SB, int n_edges) {
    __shared__ int cur[512];
    __shared__ int sb[1024];
    int t = threadIdx.x;
#pragma unroll
    for (int e = 0; e < 4; ++e) {
        int i = t + 256 * e;
        sb[i] = (i < SB) ? bsum[i] : 0;
    }
    __syncthreads();
#pragma unroll
    for (int d = 1; d < 1024; d <<= 1) {
        int xv[4];
#pragma unroll
        for (int e = 0; e < 4; ++e) {
            int i = t + 256 * e;
            xv[e] = (i >= d) ? sb[i - d] : 0;
        }
        __syncthreads();
#pragma unroll
        for (int e = 0; e < 4; ++e) sb[t + 256 * e] += xv[e];
        __syncthreads();
    }
    {
        size_t i0 = (size_t)t * NBE + blockIdx.x;
        size_t i1 = (size_t)(t + 256) * NBE + blockIdx.x;
        int j0 = (int)(i0 >> 9), j1 = (int)(i1 >> 9);
        cur[t]       = tmp[i0] + ((j0 > 0) ? sb[j0 - 1] : 0) - H[i0];
        cur[t + 256] = tmp[i1] + ((j1 > 0) ? sb[j1 - 1] : 0) - H[i1];
    }
    __syncthreads();
    if (blockIdx.x == 0) {
        bstart[t] = cur[t];
        bstart[t + 256] = cur[t + 256];
    }
    __syncthreads();

    int base = blockIdx.x * 4096;
    const int4* tgt4 = (const int4*)tgt + (base >> 2);
    const int4* src4 = (const int4*)src + (base >> 2);
#pragma unroll
    for (int r = 0; r < 4; ++r) {
        int i4 = t + 256 * r;
        int e = base + i4 * 4;
        if (e + 3 < n_edges) {
            int4 tv = tgt4[i4];
            int4 sv = src4[i4];
            int p0 = atomicAdd(&cur[tv.x & 511], 1);
            rec[p0] = ((unsigned)(tv.x >> 9) << 17) | (unsigned)sv.x;
            int p1 = atomicAdd(&cur[tv.y & 511], 1);
            rec[p1] = ((unsigned)(tv.y >> 9) << 17) | (unsigned)sv.y;
            int p2 = atomicAdd(&cur[tv.z & 511], 1);
            rec[p2] = ((unsigned)(tv.z >> 9) << 17) | (unsigned)sv.z;
            int p3 = atomicAdd(&cur[tv.w & 511], 1);
            rec[p3] = ((unsigned)(tv.w >> 9) << 17) | (unsigned)sv.w;
        } else {
            for (int q = 0; q < 4; ++q) {
                int ee = e + q;
                if (ee < n_edges) {
                    int tg = tgt[ee];
                    int pos = atomicAdd(&cur[tg & 511], 1);
                    rec[pos] = ((unsigned)(tg >> 9) << 17) | (unsigned)src[ee];
                }
            }
        }
    }
}

// csr2: one block per bucket b. Records [bstart[b], next) share tgt&511==b;
// q = rec>>17 (<196), node = b + (q<<9). LDS hist+scan -> start/cnt + scatter.
// Emits packed (code[src]<<17)|src so gathers need no node lookup.
static __global__ __launch_bounds__(256) void csr2_kernel(
        const unsigned* __restrict__ rec, const int* __restrict__ bstart,
        const unsigned short* __restrict__ code,
        unsigned* __restrict__ csr_packed,
        int* __restrict__ startA, int* __restrict__ cntA,
        int n_nodes, int n_edges) {
    __shared__ int hist[256], scn[256], cursor[256];
    __shared__ int sbeg, send;
    int b = blockIdx.x;
    int t = threadIdx.x;
    hist[t] = 0;
    if (t == 0) {
        sbeg = bstart[b];
        send = (b == 511) ? n_edges : bstart[b + 1];
    }
    __syncthreads();
    int beg = sbeg, end = send;
    for (int i = beg + t; i < end; i += 256) {
        atomicAdd(&hist[rec[i] >> 17], 1);
    }
    __syncthreads();
    scn[t] = hist[t];
    __syncthreads();
#pragma unroll
    for (int d = 1; d < 256; d <<= 1) {
        int x = (t >= d) ? scn[t - d] : 0;
        __syncthreads();
        scn[t] += x;
        __syncthreads();
    }
    int excl = scn[t] - hist[t];
    cursor[t] = beg + excl;
    int n = b + (t << 9);
    if (n < n_nodes) { startA[n] = beg + excl; cntA[n] = hist[t]; }
    __syncthreads();
    for (int i = beg + t; i < end; i += 256) {
        unsigned r = rec[i];
        unsigned s = r & 0x1FFFFu;
        unsigned cd = code[s];                 // 200KB table, L2-resident
        int p = atomicAdd(&cursor[r >> 17], 1);
        csr_packed[p] = (cd << 17) | s;
    }
}

// Layer-1 gather from LDS embedding table (staged from emb1024). 8 lanes per
// node; lane j owns cols [8j,8j+8). Row stride 20 uints for bank spread.
static __global__ __launch_bounds__(256) void gather1_kernel(
        const unsigned short* __restrict__ emb1024,
        const int* __restrict__ startA, const int* __restrict__ cntA,
        const unsigned* __restrict__ csr_packed, unsigned short* __restrict__ aggb,
        int n_nodes) {
    __shared__ __align__(16) unsigned sT[64 * 20];   // 5120B
    __shared__ __align__(16) unsigned cT[16 * 20];   // 1280B
    int t = threadIdx.x;
    const unsigned* e32 = (const unsigned*)emb1024;  // row = 32 uints
    for (int i = t; i < 64 * 16; i += 256) {
        int r = i >> 4, c = i & 15;
        sT[r * 20 + c] = e32[(size_t)(r * 16) * 32 + c];
    }
    for (int i = t; i < 16 * 16; i += 256) {
        int r = i >> 4, c = i & 15;
        cT[r * 20 + c] = e32[(size_t)r * 32 + 16 + c];
    }
    __syncthreads();

    int node = (blockIdx.x * 256 + t) >> 3;
    int j = t & 7;                           // cols [8j, 8j+8)
    if (node >= n_nodes) return;
    int beg = startA[node], deg = cntA[node];

    const uint4* sT4 = (const uint4*)sT;     // row = 5 uint4
    const uint4* cT4 = (const uint4*)cT;
    int js = j, jc = j - 4;                  // lane's block within sub-table

    float acc[8];
#pragma unroll
    for (int k = 0; k < 8; ++k) acc[k] = 0.f;

    int it = 0;
    for (; it + 3 < deg; it += 4) {
        unsigned p0 = csr_packed[beg + it];
        unsigned p1 = csr_packed[beg + it + 1];
        unsigned p2 = csr_packed[beg + it + 2];
        unsigned p3 = csr_packed[beg + it + 3];
        unsigned c0 = p0 >> 17, c1 = p1 >> 17, c2 = p2 >> 17, c3 = p3 >> 17;
        uint4 u0 = (j < 4) ? sT4[(c0 >> 4) * 5 + js] : cT4[(c0 & 15) * 5 + jc];
        uint4 u1 = (j < 4) ? sT4[(c1 >> 4) * 5 + js] : cT4[(c1 & 15) * 5 + jc];
        uint4 u2 = (j < 4) ? sT4[(c2 >> 4) * 5 + js] : cT4[(c2 & 15) * 5 + jc];
        uint4 u3 = (j < 4) ? sT4[(c3 >> 4) * 5 + js] : cT4[(c3 & 15) * 5 + jc];
        acc[0] += (blo(u0.x) + blo(u1.x)) + (blo(u2.x) + blo(u3.x));
        acc[1] += (bhi(u0.x) + bhi(u1.x)) + (bhi(u2.x) + bhi(u3.x));
        acc[2] += (blo(u0.y) + blo(u1.y)) + (blo(u2.y) + blo(u3.y));
        acc[3] += (bhi(u0.y) + bhi(u1.y)) + (bhi(u2.y) + bhi(u3.y));
        acc[4] += (blo(u0.z) + blo(u1.z)) + (blo(u2.z) + blo(u3.z));
        acc[5] += (bhi(u0.z) + bhi(u1.z)) + (bhi(u2.z) + bhi(u3.z));
        acc[6] += (blo(u0.w) + blo(u1.w)) + (blo(u2.w) + blo(u3.w));
        acc[7] += (bhi(u0.w) + bhi(u1.w)) + (bhi(u2.w) + bhi(u3.w));
    }
    for (; it < deg; ++it) {
        unsigned p0 = csr_packed[beg + it];
        unsigned c0 = p0 >> 17;
        uint4 u = (j < 4) ? sT4[(c0 >> 4) * 5 + js] : cT4[(c0 & 15) * 5 + jc];
        acc[0] += blo(u.x); acc[1] += bhi(u.x);
        acc[2] += blo(u.y); acc[3] += bhi(u.y);
        acc[4] += blo(u.z); acc[5] += bhi(u.z);
        acc[6] += blo(u.w); acc[7] += bhi(u.w);
    }
    float inv = 1.0f / fmaxf((float)deg, 1.0f);
    uint4 o;
    o.x = ((unsigned)f2b(acc[1] * inv) << 16) | f2b(acc[0] * inv);
    o.y = ((unsigned)f2b(acc[3] * inv) << 16) | f2b(acc[2] * inv);
    o.z = ((unsigned)f2b(acc[5] * inv) << 16) | f2b(acc[4] * inv);
    o.w = ((unsigned)f2b(acc[7] * inv) << 16) | f2b(acc[6] * inv);
    *reinterpret_cast<uint4*>(aggb + (size_t)node * 64 + j * 8) = o;
}

// Layer-2 gather: group-per-node, 8 lanes/node, lane j cols [8j,8j+8).
static __global__ __launch_bounds__(256) void gather_kernel(
        const unsigned short* __restrict__ h, const int* __restrict__ startA,
        const int* __restrict__ cntA,
        const unsigned* __restrict__ csr_packed, unsigned short* __restrict__ aggb,
        int n_nodes) {
    int node = (blockIdx.x * 256 + threadIdx.x) >> 3;
    int j = threadIdx.x & 7;                 // cols [8j, 8j+8)
    if (node >= n_nodes) return;
    int beg = startA[node], deg = cntA[node];

    float acc[8];
#pragma unroll
    for (int k = 0; k < 8; ++k) acc[k] = 0.f;

    const unsigned short* hj = h + j * 8;
    int it = 0;
    for (; it + 3 < deg; it += 4) {
        int s0 = (int)(csr_packed[beg + it] & 0x1FFFFu);
        int s1 = (int)(csr_packed[beg + it + 1] & 0x1FFFFu);
        int s2 = (int)(csr_packed[beg + it + 2] & 0x1FFFFu);
        int s3 = (int)(csr_packed[beg + it + 3] & 0x1FFFFu);
        uint4 u0 = *reinterpret_cast<const uint4*>(hj + (size_t)s0 * 64);
        uint4 u1 = *reinterpret_cast<const uint4*>(hj + (size_t)s1 * 64);
        uint4 u2 = *reinterpret_cast<const uint4*>(hj + (size_t)s2 * 64);
        uint4 u3 = *reinterpret_cast<const uint4*>(hj + (size_t)s3 * 64);
        acc[0] += (blo(u0.x) + blo(u1.x)) + (blo(u2.x) + blo(u3.x));
        acc[1] += (bhi(u0.x) + bhi(u1.x)) + (bhi(u2.x) + bhi(u3.x));
        acc[2] += (blo(u0.y) + blo(u1.y)) + (blo(u2.y) + blo(u3.y));
        acc[3] += (bhi(u0.y) + bhi(u1.y)) + (bhi(u2.y) + bhi(u3.y));
        acc[4] += (blo(u0.z) + blo(u1.z)) + (blo(u2.z) + blo(u3.z));
        acc[5] += (bhi(u0.z) + bhi(u1.z)) + (bhi(u2.z) + bhi(u3.z));
        acc[6] += (blo(u0.w) + blo(u1.w)) + (blo(u2.w) + blo(u3.w));
        acc[7] += (bhi(u0.w) + bhi(u1.w)) + (bhi(u2.w) + bhi(u3.w));
    }
    for (; it < deg; ++it) {
        int s = (int)(csr_packed[beg + it] & 0x1FFFFu);
        uint4 u = *reinterpret_cast<const uint4*>(hj + (size_t)s * 64);
        acc[0] += blo(u.x); acc[1] += bhi(u.x);
        acc[2] += blo(u.y); acc[3] += bhi(u.y);
        acc[4] += blo(u.z); acc[5] += bhi(u.z);
        acc[6] += blo(u.w); acc[7] += bhi(u.w);
    }
    float inv = 1.0f / fmaxf((float)deg, 1.0f);
    uint4 o;
    o.x = ((unsigned)f2b(acc[1] * inv) << 16) | f2b(acc[0] * inv);
    o.y = ((unsigned)f2b(acc[3] * inv) << 16) | f2b(acc[2] * inv);
    o.z = ((unsigned)f2b(acc[5] * inv) << 16) | f2b(acc[4] * inv);
    o.w = ((unsigned)f2b(acc[7] * inv) << 16) | f2b(acc[6] * inv);
    *reinterpret_cast<uint4*>(aggb + (size_t)node * 64 + j * 8) = o;
}

// MFMA layer (wfrag staged in LDS). Block = 4 waves; wave w owns 16 nodes.
// M=16,N=64,K=128 via 4 k-steps x 4 n-tiles x {hi,lo} mfma_f32_16x16x32_bf16.
// A-frag from global bf16 rows (aggb | self); B-frag from LDS (conflict-free
// ds_read_b128). self = h row (layer2) or emb1024[code[node]] (layer1).
// D: col=lane&15 (+nt*16), row=(lane>>4)*4+reg.
static __global__ __launch_bounds__(256) void layer_mfma_kernel(
        const unsigned short* __restrict__ aggb,
        const unsigned short* __restrict__ selfsrc,
        const unsigned short* __restrict__ code,
        const unsigned short* __restrict__ wfrag,
        const float* __restrict__ bias,
        unsigned short* __restrict__ hout, int n_nodes, int use_code) {
    __shared__ __align__(16) unsigned short wLDS[16384];   // 32KB
    int t = threadIdx.x;
    {
        const uint4* s4 = (const uint4*)wfrag;
        uint4* d4 = (uint4*)wLDS;
#pragma unroll
        for (int r = 0; r < 8; ++r) d4[t + 256 * r] = s4[t + 256 * r];
    }

    int w = t >> 6, l = t & 63;
    int row16 = l & 15, kb = l >> 4;          // kb in 0..3
    int base = blockIdx.x * 64 + w * 16;
    int node = base + row16;                  // A-row node (may be OOB; reads safe)

    const unsigned short* selfrow;
    if (use_code) {
        unsigned cd = (unsigned)code[node] & 1023u;
        selfrow = selfsrc + (size_t)cd * 64;
    } else {
        selfrow = selfsrc + (size_t)node * 64;
    }
    const unsigned short* aggrow = aggb + (size_t)node * 64;

    // prefetch A-frags before the barrier (independent of LDS)
    bf16x8 a[4];
#pragma unroll
    for (int ks = 0; ks < 4; ++ks) {
        int koff = ks * 32 + kb * 8;
        const unsigned short* ap = (ks < 2) ? (aggrow + koff)
                                            : (selfrow + (koff - 64));
        a[ks] = *(const bf16x8*)ap;
    }
    __syncthreads();

    f32x4 acc0 = {0.f, 0.f, 0.f, 0.f};
    f32x4 acc1 = {0.f, 0.f, 0.f, 0.f};
    f32x4 acc2 = {0.f, 0.f, 0.f, 0.f};
    f32x4 acc3 = {0.f, 0.f, 0.f, 0.f};

#pragma unroll
    for (int ks = 0; ks < 4; ++ks) {
        const unsigned short* wfh = wLDS + ((size_t)(0 * 4 + ks) * 4 * 64 + l) * 8;
        const unsigned short* wfl = wLDS + ((size_t)(1 * 4 + ks) * 4 * 64 + l) * 8;
#define NTILE(nt, accv)                                                          \
        {                                                                        \
            bf16x8 bh = *(const bf16x8*)(wfh + (size_t)nt * 64 * 8);             \
            bf16x8 bl = *(const bf16x8*)(wfl + (size_t)nt * 64 * 8);             \
            accv = __builtin_amdgcn_mfma_f32_16x16x32_bf16(a[ks], bh, accv, 0, 0, 0);\
            accv = __builtin_amdgcn_mfma_f32_16x16x32_bf16(a[ks], bl, accv, 0, 0, 0);\
        }
        NTILE(0, acc0) NTILE(1, acc1) NTILE(2, acc2) NTILE(3, acc3)
#undef NTILE
    }

#pragma unroll
    for (int nt = 0; nt < 4; ++nt) {
        f32x4 av = (nt == 0) ? acc0 : (nt == 1) ? acc1 : (nt == 2) ? acc2 : acc3;
        int col = nt * 16 + row16;
        float bv = bias[col];
#pragma unroll
        for (int r = 0; r < 4; ++r) {
            int orow = kb * 4 + r;
            int onode = blockIdx.x * 64 + w * 16 + orow;
            if (onode < n_nodes) {
                float v = fmaxf(av[r] + bv, 0.f);
                hout[(size_t)onode * 64 + col] = f2b(v);
            }
        }
    }
}

// batch is sorted: binary-search [start,end) per graph; mean-pool then classify.
// 1024 threads: 16 rows in flight, 2 blocks/CU across all 256 CUs.
static __global__ __launch_bounds__(1024) void pool_classify_kernel(
        const unsigned short* __restrict__ h, const int* __restrict__ batch,
        const float* __restrict__ wc, const float* __restrict__ bc,
        void* __restrict__ out, const void* probe, int n_nodes) {
    int f32 = detect_f32<1024>(probe, 1024);
    int g = blockIdx.x;
    int t = threadIdx.x;
    int lo = 0, hi = n_nodes;
    while (lo < hi) { int mid = (lo + hi) >> 1; if (batch[mid] < g) lo = mid + 1; else hi = mid; }
    int start = lo;
    hi = n_nodes;
    while (lo < hi) { int mid = (lo + hi) >> 1; if (batch[mid] < g + 1) lo = mid + 1; else hi = mid; }
    int end = lo;

    int r = t >> 6, o = t & 63;              // r in 0..15
    float partial = 0.0f;
    for (int n = start + r; n < end; n += 16) partial += b2f(h[(size_t)n * 64 + o]);
    __shared__ float sred[16][64];
    __shared__ float pooled[64];
    sred[r][o] = partial;
    __syncthreads();
    if (r == 0) {
        float cntf = fmaxf((float)(end - start), 1.0f);
        float s = 0.f;
#pragma unroll
        for (int q = 0; q < 16; ++q) s += sred[q][o];
        pooled[o] = s / cntf;
    }
    __syncthreads();
    if (t < 10) {
        float acc = bc[t];
#pragma unroll
        for (int k = 0; k < 64; ++k)
            acc = fmaf(pooled[k], wc[k * 10 + t], acc);
        if (f32) ((float*)out)[g * 10 + t] = acc;
        else     ((__hip_bfloat16*)out)[g * 10 + t] = __float2bfloat16(acc);
    }
}

extern "C" void kernel_launch(void* const* d_in, const int* in_sizes, int n_in,
                              void* d_out, int out_size, void* d_ws, size_t ws_size,
                              hipStream_t stream) {
    const int* x          = (const int*)d_in[0];
    const int* edge_index = (const int*)d_in[1];
    const int* batch      = (const int*)d_in[2];

    const int N = in_sizes[2];        // N_NODES
    const int E = in_sizes[1] / 2;    // edge_index is (2, E)
    const int G = out_size / 10;      // num_graphs

    const int NBE = (E + 4095) / 4096;          // edge tiles
    const int Hsz = 512 * NBE;                  // histogram matrix size
    const int SB  = (Hsz + 511) / 512;          // scanA blocks (== NBE, <=1024)
    const int CB  = (N + 255) / 256;            // code blocks

    // workspace layout
    unsigned short* h    = (unsigned short*)d_ws;           // N*64 bf16
    unsigned short* aggb = h + (size_t)N * 64;              // N*64 bf16
    unsigned* rec   = (unsigned*)(aggb + (size_t)N * 64);   // E packed
    int*   startA  = (int*)(rec + E);                       // N
    int*   cntA    = startA + N;                            // N
    int*   H       = cntA + N;                              // Hsz
    int*   tmpS    = H + Hsz;                               // Hsz
    int*   bsumS   = tmpS + Hsz;                            // SB (<=1024)
    int*   bstart  = bsumS + 1024;                          // 512
    unsigned* csr_packed = (unsigned*)(bstart + 512);       // E: (code<<17)|src
    unsigned short* code = (unsigned short*)(csr_packed + E); // N ushorts
    size_t NP = ((size_t)N + 7) & ~(size_t)7;               // 16B-align next
    unsigned short* emb1024 = code + NP;                    // 1024*64 bf16
    unsigned short* wfrag   = emb1024 + 1024 * 64;          // 2*2*4*4*64*8 bf16
    float* pbuf    = (float*)(wfrag + 32768);               // 778 fp32 params

    WParams wp;
    int off = 0;
    for (int i = 0; i < 10; ++i) {
        wp.p[i] = d_in[4 + i];
        wp.off[i] = off;
        off += in_sizes[4 + i];
    }
    wp.off[10] = off;

    const int* src = edge_index;
    const int* tgt = edge_index + E;

    // CSR hist + code + emb1024 + wfrag + params (multi-role)
    hist1_code_kernel<<<NBE + CB + 25, 256, 0, stream>>>(
        tgt, H, NBE, CB, x, code, wp, emb1024, wfrag, pbuf, N, E);
    scanA_kernel<<<SB, 256, 0, stream>>>(H, tmpS, bsumS, Hsz);
    scatter1_kernel<<<NBE, 256, 0, stream>>>(src, tgt, tmpS, bsumS, H, bstart,
                                             rec, NBE, SB, E);
    csr2_kernel<<<512, 256, 0, stream>>>(rec, bstart, code, csr_packed,
                                         startA, cntA, N, E);

    // layer 1: gather (high occupancy, LDS table from emb1024) + MFMA GEMM
    gather1_kernel<<<(N * 8 + 255) / 256, 256, 0, stream>>>(emb1024,
                                                            startA, cntA,
                                                            csr_packed, aggb, N);
    layer_mfma_kernel<<<(N + 63) / 64, 256, 0, stream>>>(
        aggb, emb1024, code, wfrag, pbuf, h, N, 1);

    // layer 2: gather from h + MFMA GEMM (self = h rows)
    gather_kernel<<<(N * 8 + 255) / 256, 256, 0, stream>>>(h, startA, cntA,
                                                           csr_packed, aggb, N);
    layer_mfma_kernel<<<(N + 63) / 64, 256, 0, stream>>>(
        aggb, h, code, wfrag + 16384, pbuf + 64, h, N, 0);

    // pool + classify (1024 threads: 16 rows in flight)
    pool_classify_kernel<<<G, 1024, 0, stream>>>(h, batch, pbuf + 128, pbuf + 768,
                                                 d_out, d_in[4], N);
}

// Round 12
// 225.354 us; speedup vs baseline: 1.0207x; 1.0207x over previous
//
#include <hip/hip_runtime.h>
#include <hip/hip_bf16.h>

// SPRGraphNet: embed -> 2x SAGEConv(mean) -> mean-pool per graph -> linear(64->10)
// Round 16: group-per-node gather. Round 17: LDS emb table for gather1.
// Round 18: code-only pass. Round 19: un-fused gather1 (gather needs occupancy).
// Round 20: MFMA layer kernels (wfrag pre-swizzled hi/lo bf16 weights).
// Round 21: 4-deep gather MLP (NULL -> gather is fabric-bound); convert folded.
// Round 22: lookback-scan REGRESSED (cross-XCD atomic handshake). Lesson.
// Round 23: scan reverted; pool at 1024 threads kept. 234.2us.
// Round 24: fused layer2+pool REGRESSED (hot-region global atomic bursts).
// Round 25: wfrag staged in LDS in layer_mfma. 229.9us (best).
// Round 26: scanC folded into scatter1 (NEUTRAL -- launches/tiny kernels are
// not the cost). Accounting model closes: fills 84 + gather2 ~25 (fabric
// ceiling) + layers ~22 + CSR ~25 + rest ~20 + gaps.
// Round 27: layer epilogue store repack. Old epilogue: 16 scattered 2B
// stores/thread (6.25M 2B stores/layer, 4 lines per wave store-inst). New:
// acc -> LDS f32 [64][68] (reuse dead wfrag LDS; padded, ~2-way = free) ->
// each thread packs 16 cols of one node -> 2 coalesced 16B stores.
// Identical values/rounding. 9 launches.
// Harness poison fills (~84us/iter at ~80% HBM peak) = floor.

typedef __attribute__((ext_vector_type(8))) short bf16x8;
typedef __attribute__((ext_vector_type(4))) float f32x4;

struct WParams {
    const void* p[10];
    int off[11];
};

__device__ __forceinline__ float b2f(unsigned short u) {
    return __uint_as_float(((unsigned)u) << 16);
}
__device__ __forceinline__ unsigned short f2b(float f) {
    unsigned x = __float_as_uint(f);
    return (unsigned short)((x + 0x7fff + ((x >> 16) & 1)) >> 16);   // RNE
}
__device__ __forceinline__ float blo(unsigned u) {   // low bf16 of a dword
    return __uint_as_float(u << 16);
}
__device__ __forceinline__ float bhi(unsigned u) {   // high bf16 of a dword
    return __uint_as_float(u & 0xffff0000u);
}

// Inline dtype detection: fp32 data read as bf16 shows |v|>100 / NaN.
template <int BS>
__device__ __forceinline__ int detect_f32(const void* probe, int n_bf16) {
    __shared__ int bad;
    if (threadIdx.x == 0) bad = 0;
    __syncthreads();
    const __hip_bfloat16* p = (const __hip_bfloat16*)probe;
    int lbad = 0;
    for (int i = threadIdx.x; i < n_bf16; i += BS) {
        float v = __bfloat162float(p[i]);
        if (!(fabsf(v) <= 100.0f)) lbad = 1;
    }
    if (lbad) atomicOr(&bad, 1);
    __syncthreads();
    return bad;
}

__device__ __forceinline__ float loadf(const void* p, int i, int f32) {
    return f32 ? ((const float*)p)[i]
               : __bfloat162float(((const __hip_bfloat16*)p)[i]);
}

// Blocks [0,NBE): LDS histogram of tgt&511 over a 4096-edge tile -> H[bin][blk].
// Blocks [NBE,NBE+CB): code[node] = x0*16+x1.
// Blocks [NBE+CB, +16): emb1024 bf16 table from RAW semb/cemb (detect inline).
// Blocks [NBE+CB+16, +8): wfrag (MFMA B-frag swizzled, hi/lo bf16) from RAW.
// Block  [NBE+CB+24]: pbuf fp32 params.
static __global__ __launch_bounds__(256) void hist1_code_kernel(
        const int* __restrict__ tgt, int* __restrict__ H, int NBE, int CB,
        const int* __restrict__ x, unsigned short* __restrict__ code,
        WParams wp,
        unsigned short* __restrict__ emb1024, unsigned short* __restrict__ wfrag,
        float* __restrict__ pbuf, int n_nodes, int n_edges) {
    int t = threadIdx.x;
    if (blockIdx.x < (unsigned)NBE) {
        __shared__ int lh[512];
        lh[t] = 0; lh[t + 256] = 0;
        __syncthreads();
        int base = blockIdx.x * 4096;              // multiple of 4
        const int4* tgt4 = (const int4*)tgt + (base >> 2);
#pragma unroll
        for (int r = 0; r < 4; ++r) {
            int i4 = t + 256 * r;
            int e = base + i4 * 4;
            if (e + 3 < n_edges) {
                int4 v = tgt4[i4];
                atomicAdd(&lh[v.x & 511], 1);
                atomicAdd(&lh[v.y & 511], 1);
                atomicAdd(&lh[v.z & 511], 1);
                atomicAdd(&lh[v.w & 511], 1);
            } else {
                for (int q = 0; q < 4; ++q) {
                    int ee = e + q;
                    if (ee < n_edges) atomicAdd(&lh[tgt[ee] & 511], 1);
                }
            }
        }
        __syncthreads();
        H[(size_t)t * NBE + blockIdx.x] = lh[t];
        H[(size_t)(t + 256) * NBE + blockIdx.x] = lh[t + 256];
    } else if (blockIdx.x < (unsigned)(NBE + CB)) {
        int node = (blockIdx.x - NBE) * 256 + t;
        if (node >= n_nodes) return;
        int2 xv = *(const int2*)&x[node * 2];
        code[node] = (unsigned short)(xv.x * 16 + xv.y);
    } else if (blockIdx.x < (unsigned)(NBE + CB + 16)) {
        int f32 = detect_f32<256>(wp.p[0], 1024);
        int bl = blockIdx.x - NBE - CB;
        for (int i = bl * 256 + t; i < 1024 * 64; i += 16 * 256) {
            int r = i >> 6, c = i & 63;
            float v = (c < 32) ? loadf(wp.p[0], (r >> 4) * 32 + c, f32)
                               : loadf(wp.p[1], (r & 15) * 32 + (c - 32), f32);
            emb1024[i] = f2b(v);
        }
    } else if (blockIdx.x < (unsigned)(NBE + CB + 24)) {
        int f32 = detect_f32<256>(wp.p[0], 1024);
        int bl = blockIdx.x - NBE - CB - 16;
        for (int i = bl * 256 + t; i < 32768; i += 8 * 256) {
            int j    = i & 7;
            int lane = (i >> 3) & 63;
            int nt   = (i >> 9) & 3;
            int ks   = (i >> 11) & 3;
            int part = (i >> 13) & 1;
            int L    = (i >> 14) & 1;
            int k = ks * 32 + (lane >> 4) * 8 + j;
            int c = nt * 16 + (lane & 15);
            const void* wl = L ? wp.p[5] : wp.p[2];
            const void* wr = L ? wp.p[6] : wp.p[3];
            float wv = (k < 64) ? loadf(wl, k * 64 + c, f32)
                                : loadf(wr, (k - 64) * 64 + c, f32);
            unsigned short hi = f2b(wv);
            wfrag[i] = (part == 0) ? hi : f2b(wv - b2f(hi));
        }
    } else {
        int f32 = detect_f32<256>(wp.p[0], 1024);
        for (int i = t; i < 778; i += 256) {
            float v;
            if (i < 64)       v = loadf(wp.p[4], i, f32);         // b1
            else if (i < 128) v = loadf(wp.p[7], i - 64, f32);    // b2
            else if (i < 768) v = loadf(wp.p[8], i - 128, f32);   // wc
            else              v = loadf(wp.p[9], i - 768, f32);   // bc
            pbuf[i] = v;
        }
    }
}

// scanA: 512 elements per block (2/thread), block-inclusive -> tmp, sums -> bsum.
static __global__ __launch_bounds__(256) void scanA_kernel(
        const int* __restrict__ in, int* __restrict__ tmp,
        int* __restrict__ bsum, int n) {
    __shared__ int s[256];
    int t = threadIdx.x;
    int i0 = blockIdx.x * 512 + 2 * t;
    int a0 = (i0 < n) ? in[i0] : 0;
    int a1 = (i0 + 1 < n) ? in[i0 + 1] : 0;
    s[t] = a0 + a1;
    __syncthreads();
#pragma unroll
    for (int d = 1; d < 256; d <<= 1) {
        int x = (t >= d) ? s[t - d] : 0;
        __syncthreads();
        s[t] += x;
        __syncthreads();
    }
    if (i0 < n) tmp[i0] = s[t] - a1;          // inclusive at i0
    if (i0 + 1 < n) tmp[i0 + 1] = s[t];       // inclusive at i0+1
    if (t == 255) bsum[blockIdx.x] = s[255];
}

// scatter1 (scanC folded in). Stage bsum in LDS, scan it (Hillis-Steele,
// 1024-wide), cur[bin] = tmp[bin*NBE+blk] + prefix - H[bin*NBE+blk].
// Block 0 publishes bucketStart[512] (= cur before atomics) for csr2.
// Then re-read tile; LDS cursors give global slots; write packed records.
static __global__ __launch_bounds__(256) void scatter1_kernel(
        const int* __restrict__ src, const int* __restrict__ tgt,
        const int* __restrict__ tmp, const int* __restrict__ bsum,
        const int* __restrict__ H, int* __restrict__ bstart,
        unsigned* __restrict__ rec, int NBE, int SB, int n_edges) {
    __shared__ int cur[512];
    __shared__ int sb[1024];
    int t = threadIdx.x;
#pragma unroll
    for (int e = 0; e < 4; ++e) {
        int i = t + 256 * e;
        sb[i] = (i < SB) ? bsum[i] : 0;
    }
    __syncthreads();
#pragma unroll
    for (int d = 1; d < 1024; d <<= 1) {
        int xv[4];
#pragma unroll
        for (int e = 0; e < 4; ++e) {
            int i = t + 256 * e;
            xv[e] = (i >= d) ? sb[i - d] : 0;
        }
        __syncthreads();
#pragma unroll
        for (int e = 0; e < 4; ++e) sb[t + 256 * e] += xv[e];
        __syncthreads();
    }
    {
        size_t i0 = (size_t)t * NBE + blockIdx.x;
        size_t i1 = (size_t)(t + 256) * NBE + blockIdx.x;
        int j0 = (int)(i0 >> 9), j1 = (int)(i1 >> 9);
        cur[t]       = tmp[i0] + ((j0 > 0) ? sb[j0 - 1] : 0) - H[i0];
        cur[t + 256] = tmp[i1] + ((j1 > 0) ? sb[j1 - 1] : 0) - H[i1];
    }
    __syncthreads();
    if (blockIdx.x == 0) {
        bstart[t] = cur[t];
        bstart[t + 256] = cur[t + 256];
    }
    __syncthreads();

    int base = blockIdx.x * 4096;
    const int4* tgt4 = (const int4*)tgt + (base >> 2);
    const int4* src4 = (const int4*)src + (base >> 2);
#pragma unroll
    for (int r = 0; r < 4; ++r) {
        int i4 = t + 256 * r;
        int e = base + i4 * 4;
        if (e + 3 < n_edges) {
            int4 tv = tgt4[i4];
            int4 sv = src4[i4];
            int p0 = atomicAdd(&cur[tv.x & 511], 1);
            rec[p0] = ((unsigned)(tv.x >> 9) << 17) | (unsigned)sv.x;
            int p1 = atomicAdd(&cur[tv.y & 511], 1);
            rec[p1] = ((unsigned)(tv.y >> 9) << 17) | (unsigned)sv.y;
            int p2 = atomicAdd(&cur[tv.z & 511], 1);
            rec[p2] = ((unsigned)(tv.z >> 9) << 17) | (unsigned)sv.z;
            int p3 = atomicAdd(&cur[tv.w & 511], 1);
            rec[p3] = ((unsigned)(tv.w >> 9) << 17) | (unsigned)sv.w;
        } else {
            for (int q = 0; q < 4; ++q) {
                int ee = e + q;
                if (ee < n_edges) {
                    int tg = tgt[ee];
                    int pos = atomicAdd(&cur[tg & 511], 1);
                    rec[pos] = ((unsigned)(tg >> 9) << 17) | (unsigned)src[ee];
                }
            }
        }
    }
}

// csr2: one block per bucket b. Records [bstart[b], next) share tgt&511==b;
// q = rec>>17 (<196), node = b + (q<<9). LDS hist+scan -> start/cnt + scatter.
// Emits packed (code[src]<<17)|src so gathers need no node lookup.
static __global__ __launch_bounds__(256) void csr2_kernel(
        const unsigned* __restrict__ rec, const int* __restrict__ bstart,
        const unsigned short* __restrict__ code,
        unsigned* __restrict__ csr_packed,
        int* __restrict__ startA, int* __restrict__ cntA,
        int n_nodes, int n_edges) {
    __shared__ int hist[256], scn[256], cursor[256];
    __shared__ int sbeg, send;
    int b = blockIdx.x;
    int t = threadIdx.x;
    hist[t] = 0;
    if (t == 0) {
        sbeg = bstart[b];
        send = (b == 511) ? n_edges : bstart[b + 1];
    }
    __syncthreads();
    int beg = sbeg, end = send;
    for (int i = beg + t; i < end; i += 256) {
        atomicAdd(&hist[rec[i] >> 17], 1);
    }
    __syncthreads();
    scn[t] = hist[t];
    __syncthreads();
#pragma unroll
    for (int d = 1; d < 256; d <<= 1) {
        int x = (t >= d) ? scn[t - d] : 0;
        __syncthreads();
        scn[t] += x;
        __syncthreads();
    }
    int excl = scn[t] - hist[t];
    cursor[t] = beg + excl;
    int n = b + (t << 9);
    if (n < n_nodes) { startA[n] = beg + excl; cntA[n] = hist[t]; }
    __syncthreads();
    for (int i = beg + t; i < end; i += 256) {
        unsigned r = rec[i];
        unsigned s = r & 0x1FFFFu;
        unsigned cd = code[s];                 // 200KB table, L2-resident
        int p = atomicAdd(&cursor[r >> 17], 1);
        csr_packed[p] = (cd << 17) | s;
    }
}

// Layer-1 gather from LDS embedding table (staged from emb1024). 8 lanes per
// node; lane j owns cols [8j,8j+8). Row stride 20 uints for bank spread.
static __global__ __launch_bounds__(256) void gather1_kernel(
        const unsigned short* __restrict__ emb1024,
        const int* __restrict__ startA, const int* __restrict__ cntA,
        const unsigned* __restrict__ csr_packed, unsigned short* __restrict__ aggb,
        int n_nodes) {
    __shared__ __align__(16) unsigned sT[64 * 20];   // 5120B
    __shared__ __align__(16) unsigned cT[16 * 20];   // 1280B
    int t = threadIdx.x;
    const unsigned* e32 = (const unsigned*)emb1024;  // row = 32 uints
    for (int i = t; i < 64 * 16; i += 256) {
        int r = i >> 4, c = i & 15;
        sT[r * 20 + c] = e32[(size_t)(r * 16) * 32 + c];
    }
    for (int i = t; i < 16 * 16; i += 256) {
        int r = i >> 4, c = i & 15;
        cT[r * 20 + c] = e32[(size_t)r * 32 + 16 + c];
    }
    __syncthreads();

    int node = (blockIdx.x * 256 + t) >> 3;
    int j = t & 7;                           // cols [8j, 8j+8)
    if (node >= n_nodes) return;
    int beg = startA[node], deg = cntA[node];

    const uint4* sT4 = (const uint4*)sT;     // row = 5 uint4
    const uint4* cT4 = (const uint4*)cT;
    int js = j, jc = j - 4;                  // lane's block within sub-table

    float acc[8];
#pragma unroll
    for (int k = 0; k < 8; ++k) acc[k] = 0.f;

    int it = 0;
    for (; it + 3 < deg; it += 4) {
        unsigned p0 = csr_packed[beg + it];
        unsigned p1 = csr_packed[beg + it + 1];
        unsigned p2 = csr_packed[beg + it + 2];
        unsigned p3 = csr_packed[beg + it + 3];
        unsigned c0 = p0 >> 17, c1 = p1 >> 17, c2 = p2 >> 17, c3 = p3 >> 17;
        uint4 u0 = (j < 4) ? sT4[(c0 >> 4) * 5 + js] : cT4[(c0 & 15) * 5 + jc];
        uint4 u1 = (j < 4) ? sT4[(c1 >> 4) * 5 + js] : cT4[(c1 & 15) * 5 + jc];
        uint4 u2 = (j < 4) ? sT4[(c2 >> 4) * 5 + js] : cT4[(c2 & 15) * 5 + jc];
        uint4 u3 = (j < 4) ? sT4[(c3 >> 4) * 5 + js] : cT4[(c3 & 15) * 5 + jc];
        acc[0] += (blo(u0.x) + blo(u1.x)) + (blo(u2.x) + blo(u3.x));
        acc[1] += (bhi(u0.x) + bhi(u1.x)) + (bhi(u2.x) + bhi(u3.x));
        acc[2] += (blo(u0.y) + blo(u1.y)) + (blo(u2.y) + blo(u3.y));
        acc[3] += (bhi(u0.y) + bhi(u1.y)) + (bhi(u2.y) + bhi(u3.y));
        acc[4] += (blo(u0.z) + blo(u1.z)) + (blo(u2.z) + blo(u3.z));
        acc[5] += (bhi(u0.z) + bhi(u1.z)) + (bhi(u2.z) + bhi(u3.z));
        acc[6] += (blo(u0.w) + blo(u1.w)) + (blo(u2.w) + blo(u3.w));
        acc[7] += (bhi(u0.w) + bhi(u1.w)) + (bhi(u2.w) + bhi(u3.w));
    }
    for (; it < deg; ++it) {
        unsigned p0 = csr_packed[beg + it];
        unsigned c0 = p0 >> 17;
        uint4 u = (j < 4) ? sT4[(c0 >> 4) * 5 + js] : cT4[(c0 & 15) * 5 + jc];
        acc[0] += blo(u.x); acc[1] += bhi(u.x);
        acc[2] += blo(u.y); acc[3] += bhi(u.y);
        acc[4] += blo(u.z); acc[5] += bhi(u.z);
        acc[6] += blo(u.w); acc[7] += bhi(u.w);
    }
    float inv = 1.0f / fmaxf((float)deg, 1.0f);
    uint4 o;
    o.x = ((unsigned)f2b(acc[1] * inv) << 16) | f2b(acc[0] * inv);
    o.y = ((unsigned)f2b(acc[3] * inv) << 16) | f2b(acc[2] * inv);
    o.z = ((unsigned)f2b(acc[5] * inv) << 16) | f2b(acc[4] * inv);
    o.w = ((unsigned)f2b(acc[7] * inv) << 16) | f2b(acc[6] * inv);
    *reinterpret_cast<uint4*>(aggb + (size_t)node * 64 + j * 8) = o;
}

// Layer-2 gather: group-per-node, 8 lanes/node, lane j cols [8j,8j+8).
static __global__ __launch_bounds__(256) void gather_kernel(
        const unsigned short* __restrict__ h, const int* __restrict__ startA,
        const int* __restrict__ cntA,
        const unsigned* __restrict__ csr_packed, unsigned short* __restrict__ aggb,
        int n_nodes) {
    int node = (blockIdx.x * 256 + threadIdx.x) >> 3;
    int j = threadIdx.x & 7;                 // cols [8j, 8j+8)
    if (node >= n_nodes) return;
    int beg = startA[node], deg = cntA[node];

    float acc[8];
#pragma unroll
    for (int k = 0; k < 8; ++k) acc[k] = 0.f;

    const unsigned short* hj = h + j * 8;
    int it = 0;
    for (; it + 3 < deg; it += 4) {
        int s0 = (int)(csr_packed[beg + it] & 0x1FFFFu);
        int s1 = (int)(csr_packed[beg + it + 1] & 0x1FFFFu);
        int s2 = (int)(csr_packed[beg + it + 2] & 0x1FFFFu);
        int s3 = (int)(csr_packed[beg + it + 3] & 0x1FFFFu);
        uint4 u0 = *reinterpret_cast<const uint4*>(hj + (size_t)s0 * 64);
        uint4 u1 = *reinterpret_cast<const uint4*>(hj + (size_t)s1 * 64);
        uint4 u2 = *reinterpret_cast<const uint4*>(hj + (size_t)s2 * 64);
        uint4 u3 = *reinterpret_cast<const uint4*>(hj + (size_t)s3 * 64);
        acc[0] += (blo(u0.x) + blo(u1.x)) + (blo(u2.x) + blo(u3.x));
        acc[1] += (bhi(u0.x) + bhi(u1.x)) + (bhi(u2.x) + bhi(u3.x));
        acc[2] += (blo(u0.y) + blo(u1.y)) + (blo(u2.y) + blo(u3.y));
        acc[3] += (bhi(u0.y) + bhi(u1.y)) + (bhi(u2.y) + bhi(u3.y));
        acc[4] += (blo(u0.z) + blo(u1.z)) + (blo(u2.z) + blo(u3.z));
        acc[5] += (bhi(u0.z) + bhi(u1.z)) + (bhi(u2.z) + bhi(u3.z));
        acc[6] += (blo(u0.w) + blo(u1.w)) + (blo(u2.w) + blo(u3.w));
        acc[7] += (bhi(u0.w) + bhi(u1.w)) + (bhi(u2.w) + bhi(u3.w));
    }
    for (; it < deg; ++it) {
        int s = (int)(csr_packed[beg + it] & 0x1FFFFu);
        uint4 u = *reinterpret_cast<const uint4*>(hj + (size_t)s * 64);
        acc[0] += blo(u.x); acc[1] += bhi(u.x);
        acc[2] += blo(u.y); acc[3] += bhi(u.y);
        acc[4] += blo(u.z); acc[5] += bhi(u.z);
        acc[6] += blo(u.w); acc[7] += bhi(u.w);
    }
    float inv = 1.0f / fmaxf((float)deg, 1.0f);
    uint4 o;
    o.x = ((unsigned)f2b(acc[1] * inv) << 16) | f2b(acc[0] * inv);
    o.y = ((unsigned)f2b(acc[3] * inv) << 16) | f2b(acc[2] * inv);
    o.z = ((unsigned)f2b(acc[5] * inv) << 16) | f2b(acc[4] * inv);
    o.w = ((unsigned)f2b(acc[7] * inv) << 16) | f2b(acc[6] * inv);
    *reinterpret_cast<uint4*>(aggb + (size_t)node * 64 + j * 8) = o;
}

// MFMA layer (wfrag staged in LDS; R27 repacked epilogue). Block = 4 waves;
// wave w owns 16 nodes. M=16,N=64,K=128 via 4 k-steps x 4 n-tiles x {hi,lo}
// mfma_f32_16x16x32_bf16. A-frag from global bf16 rows (aggb | self); B-frag
// from LDS. Epilogue: relu(acc+bias) -> LDS f32 [64][68] (reusing wLDS) ->
// each thread packs 16 cols of one node -> 2 coalesced 16B stores.
static __global__ __launch_bounds__(256) void layer_mfma_kernel(
        const unsigned short* __restrict__ aggb,
        const unsigned short* __restrict__ selfsrc,
        const unsigned short* __restrict__ code,
        const unsigned short* __restrict__ wfrag,
        const float* __restrict__ bias,
        unsigned short* __restrict__ hout, int n_nodes, int use_code) {
    __shared__ __align__(16) unsigned short wLDS[16384];   // 32KB (reused by epilogue)
    int t = threadIdx.x;
    {
        const uint4* s4 = (const uint4*)wfrag;
        uint4* d4 = (uint4*)wLDS;
#pragma unroll
        for (int r = 0; r < 8; ++r) d4[t + 256 * r] = s4[t + 256 * r];
    }

    int w = t >> 6, l = t & 63;
    int row16 = l & 15, kb = l >> 4;          // kb in 0..3
    int base = blockIdx.x * 64 + w * 16;
    int node = base + row16;                  // A-row node (may be OOB; reads safe)

    const unsigned short* selfrow;
    if (use_code) {
        unsigned cd = (unsigned)code[node] & 1023u;
        selfrow = selfsrc + (size_t)cd * 64;
    } else {
        selfrow = selfsrc + (size_t)node * 64;
    }
    const unsigned short* aggrow = aggb + (size_t)node * 64;

    // prefetch A-frags before the barrier (independent of LDS)
    bf16x8 a[4];
#pragma unroll
    for (int ks = 0; ks < 4; ++ks) {
        int koff = ks * 32 + kb * 8;
        const unsigned short* ap = (ks < 2) ? (aggrow + koff)
                                            : (selfrow + (koff - 64));
        a[ks] = *(const bf16x8*)ap;
    }
    __syncthreads();

    f32x4 acc0 = {0.f, 0.f, 0.f, 0.f};
    f32x4 acc1 = {0.f, 0.f, 0.f, 0.f};
    f32x4 acc2 = {0.f, 0.f, 0.f, 0.f};
    f32x4 acc3 = {0.f, 0.f, 0.f, 0.f};

#pragma unroll
    for (int ks = 0; ks < 4; ++ks) {
        const unsigned short* wfh = wLDS + ((size_t)(0 * 4 + ks) * 4 * 64 + l) * 8;
        const unsigned short* wfl = wLDS + ((size_t)(1 * 4 + ks) * 4 * 64 + l) * 8;
#define NTILE(nt, accv)                                                          \
        {                                                                        \
            bf16x8 bh = *(const bf16x8*)(wfh + (size_t)nt * 64 * 8);             \
            bf16x8 bl = *(const bf16x8*)(wfl + (size_t)nt * 64 * 8);             \
            accv = __builtin_amdgcn_mfma_f32_16x16x32_bf16(a[ks], bh, accv, 0, 0, 0);\
            accv = __builtin_amdgcn_mfma_f32_16x16x32_bf16(a[ks], bl, accv, 0, 0, 0);\
        }
        NTILE(0, acc0) NTILE(1, acc1) NTILE(2, acc2) NTILE(3, acc3)
#undef NTILE
    }

    // R27 epilogue: acc -> LDS f32 [64][68] -> coalesced 16B bf16 stores.
    float* sF = (float*)wLDS;                 // 64*68*4 = 17408B <= 32KB
    __syncthreads();                          // all wLDS B-frag reads done
#pragma unroll
    for (int nt = 0; nt < 4; ++nt) {
        f32x4 av = (nt == 0) ? acc0 : (nt == 1) ? acc1 : (nt == 2) ? acc2 : acc3;
        float bv = bias[nt * 16 + row16];
#pragma unroll
        for (int r = 0; r < 4; ++r) {
            sF[(w * 16 + kb * 4 + r) * 68 + nt * 16 + row16] =
                fmaxf(av[r] + bv, 0.f);
        }
    }
    __syncthreads();
    {
        int n = t >> 2, seg = t & 3;          // node-local row, 16-col segment
        int onode = blockIdx.x * 64 + n;
        if (onode < n_nodes) {
            const float* rowp = sF + n * 68 + seg * 16;
            uint4 o0, o1;
            o0.x = ((unsigned)f2b(rowp[1])  << 16) | f2b(rowp[0]);
            o0.y = ((unsigned)f2b(rowp[3])  << 16) | f2b(rowp[2]);
            o0.z = ((unsigned)f2b(rowp[5])  << 16) | f2b(rowp[4]);
            o0.w = ((unsigned)f2b(rowp[7])  << 16) | f2b(rowp[6]);
            o1.x = ((unsigned)f2b(rowp[9])  << 16) | f2b(rowp[8]);
            o1.y = ((unsigned)f2b(rowp[11]) << 16) | f2b(rowp[10]);
            o1.z = ((unsigned)f2b(rowp[13]) << 16) | f2b(rowp[12]);
            o1.w = ((unsigned)f2b(rowp[15]) << 16) | f2b(rowp[14]);
            uint4* dst = (uint4*)(hout + (size_t)onode * 64 + seg * 16);
            dst[0] = o0;
            dst[1] = o1;
        }
    }
}

// batch is sorted: binary-search [start,end) per graph; mean-pool then classify.
// 1024 threads: 16 rows in flight, 2 blocks/CU across all 256 CUs.
static __global__ __launch_bounds__(1024) void pool_classify_kernel(
        const unsigned short* __restrict__ h, const int* __restrict__ batch,
        const float* __restrict__ wc, const float* __restrict__ bc,
        void* __restrict__ out, const void* probe, int n_nodes) {
    int f32 = detect_f32<1024>(probe, 1024);
    int g = blockIdx.x;
    int t = threadIdx.x;
    int lo = 0, hi = n_nodes;
    while (lo < hi) { int mid = (lo + hi) >> 1; if (batch[mid] < g) lo = mid + 1; else hi = mid; }
    int start = lo;
    hi = n_nodes;
    while (lo < hi) { int mid = (lo + hi) >> 1; if (batch[mid] < g + 1) lo = mid + 1; else hi = mid; }
    int end = lo;

    int r = t >> 6, o = t & 63;              // r in 0..15
    float partial = 0.0f;
    for (int n = start + r; n < end; n += 16) partial += b2f(h[(size_t)n * 64 + o]);
    __shared__ float sred[16][64];
    __shared__ float pooled[64];
    sred[r][o] = partial;
    __syncthreads();
    if (r == 0) {
        float cntf = fmaxf((float)(end - start), 1.0f);
        float s = 0.f;
#pragma unroll
        for (int q = 0; q < 16; ++q) s += sred[q][o];
        pooled[o] = s / cntf;
    }
    __syncthreads();
    if (t < 10) {
        float acc = bc[t];
#pragma unroll
        for (int k = 0; k < 64; ++k)
            acc = fmaf(pooled[k], wc[k * 10 + t], acc);
        if (f32) ((float*)out)[g * 10 + t] = acc;
        else     ((__hip_bfloat16*)out)[g * 10 + t] = __float2bfloat16(acc);
    }
}

extern "C" void kernel_launch(void* const* d_in, const int* in_sizes, int n_in,
                              void* d_out, int out_size, void* d_ws, size_t ws_size,
                              hipStream_t stream) {
    const int* x          = (const int*)d_in[0];
    const int* edge_index = (const int*)d_in[1];
    const int* batch      = (const int*)d_in[2];

    const int N = in_sizes[2];        // N_NODES
    const int E = in_sizes[1] / 2;    // edge_index is (2, E)
    const int G = out_size / 10;      // num_graphs

    const int NBE = (E + 4095) / 4096;          // edge tiles
    const int Hsz = 512 * NBE;                  // histogram matrix size
    const int SB  = (Hsz + 511) / 512;          // scanA blocks (== NBE, <=1024)
    const int CB  = (N + 255) / 256;            // code blocks

    // workspace layout
    unsigned short* h    = (unsigned short*)d_ws;           // N*64 bf16
    unsigned short* aggb = h + (size_t)N * 64;              // N*64 bf16
    unsigned* rec   = (unsigned*)(aggb + (size_t)N * 64);   // E packed
    int*   startA  = (int*)(rec + E);                       // N
    int*   cntA    = startA + N;                            // N
    int*   H       = cntA + N;                              // Hsz
    int*   tmpS    = H + Hsz;                               // Hsz
    int*   bsumS   = tmpS + Hsz;                            // SB (<=1024)
    int*   bstart  = bsumS + 1024;                          // 512
    unsigned* csr_packed = (unsigned*)(bstart + 512);       // E: (code<<17)|src
    unsigned short* code = (unsigned short*)(csr_packed + E); // N ushorts
    size_t NP = ((size_t)N + 7) & ~(size_t)7;               // 16B-align next
    unsigned short* emb1024 = code + NP;                    // 1024*64 bf16
    unsigned short* wfrag   = emb1024 + 1024 * 64;          // 2*2*4*4*64*8 bf16
    float* pbuf    = (float*)(wfrag + 32768);               // 778 fp32 params

    WParams wp;
    int off = 0;
    for (int i = 0; i < 10; ++i) {
        wp.p[i] = d_in[4 + i];
        wp.off[i] = off;
        off += in_sizes[4 + i];
    }
    wp.off[10] = off;

    const int* src = edge_index;
    const int* tgt = edge_index + E;

    // CSR hist + code + emb1024 + wfrag + params (multi-role)
    hist1_code_kernel<<<NBE + CB + 25, 256, 0, stream>>>(
        tgt, H, NBE, CB, x, code, wp, emb1024, wfrag, pbuf, N, E);
    scanA_kernel<<<SB, 256, 0, stream>>>(H, tmpS, bsumS, Hsz);
    scatter1_kernel<<<NBE, 256, 0, stream>>>(src, tgt, tmpS, bsumS, H, bstart,
                                             rec, NBE, SB, E);
    csr2_kernel<<<512, 256, 0, stream>>>(rec, bstart, code, csr_packed,
                                         startA, cntA, N, E);

    // layer 1: gather (high occupancy, LDS table from emb1024) + MFMA GEMM
    gather1_kernel<<<(N * 8 + 255) / 256, 256, 0, stream>>>(emb1024,
                                                            startA, cntA,
                                                            csr_packed, aggb, N);
    layer_mfma_kernel<<<(N + 63) / 64, 256, 0, stream>>>(
        aggb, emb1024, code, wfrag, pbuf, h, N, 1);

    // layer 2: gather from h + MFMA GEMM (self = h rows)
    gather_kernel<<<(N * 8 + 255) / 256, 256, 0, stream>>>(h, startA, cntA,
                                                           csr_packed, aggb, N);
    layer_mfma_kernel<<<(N + 63) / 64, 256, 0, stream>>>(
        aggb, h, code, wfrag + 16384, pbuf + 64, h, N, 0);

    // pool + classify (1024 threads: 16 rows in flight)
    pool_classify_kernel<<<G, 1024, 0, stream>>>(h, batch, pbuf + 128, pbuf + 768,
                                                 d_out, d_in[4], N);
}